// Round 1
// baseline (389.702 us; speedup 1.0000x reference)
//
#include <hip/hip_runtime.h>
#include <stdint.h>

#define IN_F   4096
#define OUT_F  4096
#define M_TOT  8192
#define KDIM   4096

typedef float          f32x4  __attribute__((ext_vector_type(4)));
typedef int            i32x4  __attribute__((ext_vector_type(4)));
typedef unsigned short u16x8  __attribute__((ext_vector_type(8)));
typedef __bf16         bf16x8 __attribute__((ext_vector_type(8)));

// round-to-nearest-even f32 -> bf16
__device__ __forceinline__ unsigned short f2bf(float f) {
  uint32_t u = __builtin_bit_cast(uint32_t, f);
  u = (u + 0x7FFFu + ((u >> 16) & 1u)) >> 16;
  return (unsigned short)u;
}

// async global->LDS, 16B per lane; LDS dest is wave-uniform base + lane*16
__device__ __forceinline__ void gld_lds16(const void* g, void* l) {
  __builtin_amdgcn_global_load_lds((const __attribute__((address_space(1))) void*)g,
                                   (__attribute__((address_space(3))) void*)l,
                                   16, 0, 0);
}

// ---------- kernel 1: x (fp32) -> bf16, 8 elems/thread ----------
__global__ __launch_bounds__(256) void k_xcast(const f32x4* __restrict__ x,
                                               u16x8* __restrict__ xb) {
  int t = blockIdx.x * 256 + threadIdx.x;   // 4,194,304 threads exactly
  f32x4 a = x[2 * t];
  f32x4 b = x[2 * t + 1];
  u16x8 o;
  o[0] = f2bf(a[0]); o[1] = f2bf(a[1]); o[2] = f2bf(a[2]); o[3] = f2bf(a[3]);
  o[4] = f2bf(b[0]); o[5] = f2bf(b[1]); o[6] = f2bf(b[2]); o[7] = f2bf(b[3]);
  xb[t] = o;
}

// ---------- kernel 2: L[o][i] = 2.0 * sum_r A[i][r]*B[r][o]  (fp32, into d_out scratch) ----------
__global__ __launch_bounds__(256) void k_lora(const float* __restrict__ A,   // [IN_F][16]
                                              const float* __restrict__ Bm,  // [16][OUT_F]
                                              float* __restrict__ L) {       // [OUT_F][IN_F]
  __shared__ float sB[16][64];
  const int ib = blockIdx.x * 256;  // i base
  const int ob = blockIdx.y * 64;   // o base
  const int t  = threadIdx.x;
  for (int j = 0; j < 4; ++j) {
    int idx = t + j * 256;          // idx = r*64 + oc
    int r = idx >> 6, oc = idx & 63;
    sB[r][oc] = Bm[r * OUT_F + ob + oc];
  }
  float a[16];
  const f32x4* Ap = (const f32x4*)(A + (size_t)(ib + t) * 16);
  #pragma unroll
  for (int j = 0; j < 4; ++j) {
    f32x4 v = Ap[j];
    a[4*j+0] = v[0]; a[4*j+1] = v[1]; a[4*j+2] = v[2]; a[4*j+3] = v[3];
  }
  __syncthreads();
  float* Lp = L + (size_t)ob * IN_F + ib + t;
  #pragma unroll 4
  for (int oc = 0; oc < 64; ++oc) {
    float acc = 0.f;
    #pragma unroll
    for (int r = 0; r < 16; ++r) acc += a[r] * sB[r][oc];
    Lp[(size_t)oc * IN_F] = acc * 2.0f;   // LORA_SCALE = 32/16
  }
}

// ---------- kernel 3: dequant INT4 + merge L -> Wc bf16 [OUT_F][IN_F] ----------
__global__ __launch_bounds__(256) void k_dequant(const int* __restrict__ idx,
                                                 const float* __restrict__ cb,
                                                 const float* __restrict__ scales,
                                                 const float* __restrict__ L,
                                                 unsigned short* __restrict__ Wc) {
  __shared__ float scb[16];
  const int t = blockIdx.x * 256 + threadIdx.x;   // 2,097,152 threads, 8 weights each
  if (threadIdx.x < 16) scb[threadIdx.x] = cb[threadIdx.x];
  __syncthreads();
  i32x4 w = ((const i32x4*)idx)[t];
  float sc = scales[t >> 4];                      // group = (t*8)/128
  f32x4 l0 = ((const f32x4*)L)[2 * t];
  f32x4 l1 = ((const f32x4*)L)[2 * t + 1];
  float lv[8] = {l0[0], l0[1], l0[2], l0[3], l1[0], l1[1], l1[2], l1[3]};
  u16x8 o;
  #pragma unroll
  for (int j = 0; j < 4; ++j) {
    int word = w[j];
    float v0 = scb[word & 15] * sc + lv[2 * j];
    float v1 = scb[(word >> 4) & 15] * sc + lv[2 * j + 1];
    o[2 * j]     = f2bf(v0);
    o[2 * j + 1] = f2bf(v1);
  }
  ((u16x8*)Wc)[t] = o;
}

// ---------- kernel 4: bf16 GEMM  C[m][n] = sum_k A[m][k]*B[n][k] + bias[n] ----------
// 128x128 tile, BK=64, 256 threads = 4 waves (2x2), each wave 64x64 output.
__global__ __launch_bounds__(256) void k_gemm(const unsigned short* __restrict__ A, // [M_TOT][KDIM] bf16
                                              const unsigned short* __restrict__ B, // [OUT_F][KDIM] bf16
                                              const float* __restrict__ bias,
                                              float* __restrict__ C) {              // [M_TOT][OUT_F] f32
  __shared__ unsigned short sA[128 * 64];
  __shared__ unsigned short sB[128 * 64];
  const int t    = threadIdx.x;
  const int wave = t >> 6;
  const int lane = t & 63;
  const int wm   = wave >> 1;   // 0..1 row-half
  const int wn   = wave & 1;    // 0..1 col-half
  const int bm   = blockIdx.x;  // 0..63
  const int bn   = blockIdx.y;  // 0..31

  const int r = lane & 15;
  const int q = lane >> 4;

  const int srow = t >> 3;        // 0..31 (+ j*32)
  const int scol = (t & 7) * 8;   // element col within BK=64

  const unsigned short* Ab = A + (size_t)(bm * 128) * KDIM;
  const unsigned short* Bb = B + (size_t)(bn * 128) * KDIM;

  f32x4 acc[4][4];
  #pragma unroll
  for (int m = 0; m < 4; ++m)
    #pragma unroll
    for (int n = 0; n < 4; ++n)
      acc[m][n] = (f32x4){0.f, 0.f, 0.f, 0.f};

  for (int kt = 0; kt < KDIM / 64; ++kt) {
    const int k0 = kt * 64;
    #pragma unroll
    for (int j = 0; j < 4; ++j)
      gld_lds16(Ab + (size_t)(j * 32 + srow) * KDIM + k0 + scol, &sA[j * 2048 + wave * 512]);
    #pragma unroll
    for (int j = 0; j < 4; ++j)
      gld_lds16(Bb + (size_t)(j * 32 + srow) * KDIM + k0 + scol, &sB[j * 2048 + wave * 512]);
    __syncthreads();   // compiler drains vmcnt before barrier -> LDS tile valid

    #pragma unroll
    for (int kk = 0; kk < 2; ++kk) {
      bf16x8 af[4], bfr[4];
      #pragma unroll
      for (int m = 0; m < 4; ++m)
        af[m] = *(const bf16x8*)&sA[(wm * 64 + m * 16 + r) * 64 + kk * 32 + q * 8];
      #pragma unroll
      for (int n = 0; n < 4; ++n)
        bfr[n] = *(const bf16x8*)&sB[(wn * 64 + n * 16 + r) * 64 + kk * 32 + q * 8];
      #pragma unroll
      for (int m = 0; m < 4; ++m)
        #pragma unroll
        for (int n = 0; n < 4; ++n)
          acc[m][n] = __builtin_amdgcn_mfma_f32_16x16x32_bf16(af[m], bfr[n], acc[m][n], 0, 0, 0);
    }
    __syncthreads();
  }

  // epilogue: C = acc + bias  (C/D layout: col = lane&15, row = (lane>>4)*4 + j)
  const int row0 = bm * 128 + wm * 64;
  const int col0 = bn * 128 + wn * 64;
  float bv[4];
  #pragma unroll
  for (int n = 0; n < 4; ++n) bv[n] = bias[col0 + n * 16 + r];
  #pragma unroll
  for (int m = 0; m < 4; ++m) {
    #pragma unroll
    for (int j = 0; j < 4; ++j) {
      const int row = row0 + m * 16 + q * 4 + j;
      float* Cp = C + (size_t)row * OUT_F + col0 + r;
      #pragma unroll
      for (int n = 0; n < 4; ++n)
        Cp[n * 16] = acc[m][n][j] + bv[n];
    }
  }
}

extern "C" void kernel_launch(void* const* d_in, const int* in_sizes, int n_in,
                              void* d_out, int out_size, void* d_ws, size_t ws_size,
                              hipStream_t stream) {
  const float* x    = (const float*)d_in[0];
  const int*   idx  = (const int*)d_in[1];
  const float* cb   = (const float*)d_in[2];
  const float* scl  = (const float*)d_in[3];
  const float* lA   = (const float*)d_in[4];
  const float* lB   = (const float*)d_in[5];
  const float* bias = (const float*)d_in[6];
  float* out = (float*)d_out;

  // workspace layout: [0,64MB) x_bf16 ; [64MB,96MB) Wc bf16
  unsigned short* xb = (unsigned short*)d_ws;
  unsigned short* Wc = (unsigned short*)((char*)d_ws + (size_t)M_TOT * KDIM * 2);
  // LoRA matrix L[OUT_F][IN_F] fp32: use d_out as scratch (overwritten by k_gemm)
  float* Lbuf = out;

  k_xcast<<<16384, 256, 0, stream>>>((const f32x4*)x, (u16x8*)xb);
  k_lora<<<dim3(16, 64), 256, 0, stream>>>(lA, lB, Lbuf);
  k_dequant<<<8192, 256, 0, stream>>>(idx, cb, scl, Lbuf, Wc);
  k_gemm<<<dim3(64, 32), 256, 0, stream>>>(xb, Wc, bias, out);
}

// Round 4
// 289.819 us; speedup vs baseline: 1.3446x; 1.3446x over previous
//
#include <hip/hip_runtime.h>
#include <stdint.h>

#define IN_F   4096
#define OUT_F  4096
#define M_TOT  8192
#define KDIM   4096

typedef float          f32x4  __attribute__((ext_vector_type(4)));
typedef int            i32x4  __attribute__((ext_vector_type(4)));
typedef unsigned short u16x8  __attribute__((ext_vector_type(8)));
typedef __bf16         bf16x8 __attribute__((ext_vector_type(8)));

// round-to-nearest-even f32 -> bf16
__device__ __forceinline__ unsigned short f2bf(float f) {
  uint32_t u = __builtin_bit_cast(uint32_t, f);
  u = (u + 0x7FFFu + ((u >> 16) & 1u)) >> 16;
  return (unsigned short)u;
}

// async global->LDS, 16B/lane; LDS dest = wave-uniform base + lane*16 (linear)
__device__ __forceinline__ void gld_lds16(const void* g, void* l) {
  __builtin_amdgcn_global_load_lds((const __attribute__((address_space(1))) void*)g,
                                   (__attribute__((address_space(3))) void*)l,
                                   16, 0, 0);
}

// ---------- kernel 1: x (fp32) -> bf16, 8 elems/thread ----------
__global__ __launch_bounds__(256) void k_xcast(const f32x4* __restrict__ x,
                                               u16x8* __restrict__ xb) {
  int t = blockIdx.x * 256 + threadIdx.x;
  f32x4 a = x[2 * t];
  f32x4 b = x[2 * t + 1];
  u16x8 o;
  o[0] = f2bf(a[0]); o[1] = f2bf(a[1]); o[2] = f2bf(a[2]); o[3] = f2bf(a[3]);
  o[4] = f2bf(b[0]); o[5] = f2bf(b[1]); o[6] = f2bf(b[2]); o[7] = f2bf(b[3]);
  xb[t] = o;
}

// ---------- kernel 2: L[o][i] = 2.0 * sum_r A[i][r]*B[r][o]  (fp32, into d_out scratch) ----------
__global__ __launch_bounds__(256) void k_lora(const float* __restrict__ A,   // [IN_F][16]
                                              const float* __restrict__ Bm,  // [16][OUT_F]
                                              float* __restrict__ L) {       // [OUT_F][IN_F]
  __shared__ float sB[16][64];
  const int ib = blockIdx.x * 256;
  const int ob = blockIdx.y * 64;
  const int t  = threadIdx.x;
  for (int j = 0; j < 4; ++j) {
    int idx = t + j * 256;
    int r = idx >> 6, oc = idx & 63;
    sB[r][oc] = Bm[r * OUT_F + ob + oc];
  }
  float a[16];
  const f32x4* Ap = (const f32x4*)(A + (size_t)(ib + t) * 16);
  #pragma unroll
  for (int j = 0; j < 4; ++j) {
    f32x4 v = Ap[j];
    a[4*j+0] = v[0]; a[4*j+1] = v[1]; a[4*j+2] = v[2]; a[4*j+3] = v[3];
  }
  __syncthreads();
  float* Lp = L + (size_t)ob * IN_F + ib + t;
  #pragma unroll 4
  for (int oc = 0; oc < 64; ++oc) {
    float acc = 0.f;
    #pragma unroll
    for (int r = 0; r < 16; ++r) acc += a[r] * sB[r][oc];
    Lp[(size_t)oc * IN_F] = acc * 2.0f;
  }
}

// ---------- kernel 3: dequant INT4 + merge L -> Wc bf16 [OUT_F][IN_F] ----------
__global__ __launch_bounds__(256) void k_dequant(const int* __restrict__ idx,
                                                 const float* __restrict__ cb,
                                                 const float* __restrict__ scales,
                                                 const float* __restrict__ L,
                                                 unsigned short* __restrict__ Wc) {
  __shared__ float scb[16];
  const int t = blockIdx.x * 256 + threadIdx.x;
  if (threadIdx.x < 16) scb[threadIdx.x] = cb[threadIdx.x];
  __syncthreads();
  i32x4 w = ((const i32x4*)idx)[t];
  float sc = scales[t >> 4];
  f32x4 l0 = ((const f32x4*)L)[2 * t];
  f32x4 l1 = ((const f32x4*)L)[2 * t + 1];
  float lv[8] = {l0[0], l0[1], l0[2], l0[3], l1[0], l1[1], l1[2], l1[3]};
  u16x8 o;
  #pragma unroll
  for (int j = 0; j < 4; ++j) {
    int word = w[j];
    float v0 = scb[word & 15] * sc + lv[2 * j];
    float v1 = scb[(word >> 4) & 15] * sc + lv[2 * j + 1];
    o[2 * j]     = f2bf(v0);
    o[2 * j + 1] = f2bf(v1);
  }
  ((u16x8*)Wc)[t] = o;
}

// ---------- kernel 4: 256x256 8-phase bf16 GEMM (m201-style template) ----------
// C[m][n] = sum_k A[m][k]*B[n][k] + bias[n];  A:[8192][4096] bf16, B:[4096][4096] bf16.
// 512 threads = 8 waves (2M x 4N); per-wave output 128x64; BK=64; 128 KiB static LDS dbuf.
// LDS layout (bytes): A buf c at c*32768 (256 rows x 128B); B buf c at 65536+c*32768.
// Swizzle: logical 16B-slot s of row is stored at physical slot s^(row&7);
// applied via pre-swizzled global source (linear gld_lds dest) + XOR on ds_read.

#define BARR()  __builtin_amdgcn_s_barrier()
#define LGKM0() asm volatile("s_waitcnt lgkmcnt(0)" ::: "memory")
#define VMC6()  asm volatile("s_waitcnt vmcnt(6)" ::: "memory")
#define VMC0()  asm volatile("s_waitcnt vmcnt(0)" ::: "memory")

#define STAGE_A(kt, ha, c) do {                                                          \
  gld_lds16(Ag + (size_t)((ha) * 128) * KDIM + (kt) * 64,                                \
            smem + (c) * 32768 + (ha) * 16384 + ldsw);                                   \
  gld_lds16(Ag + (size_t)((ha) * 128 + 64) * KDIM + (kt) * 64,                           \
            smem + (c) * 32768 + (ha) * 16384 + 8192 + ldsw);                            \
} while (0)

#define STAGE_B(kt, hb, c) do {                                                          \
  gld_lds16(Bg + (size_t)((hb) * 128) * KDIM + (kt) * 64,                                \
            smem + 65536 + (c) * 32768 + (hb) * 16384 + ldsw);                           \
  gld_lds16(Bg + (size_t)((hb) * 128 + 64) * KDIM + (kt) * 64,                           \
            smem + 65536 + (c) * 32768 + (hb) * 16384 + 8192 + ldsw);                    \
} while (0)

#define LOAD_A(qm, c) do {                                                               \
  const char* _p = smem + (c) * 32768 + rowA + (qm) * 8192;                              \
  _Pragma("unroll")                                                                      \
  for (int mi = 0; mi < 4; ++mi) {                                                       \
    af[mi][0] = *(const bf16x8*)(_p + mi * 2048 + coff0);                                \
    af[mi][1] = *(const bf16x8*)(_p + mi * 2048 + coff1);                                \
  }                                                                                      \
} while (0)

#define LOAD_B(c) do {                                                                   \
  const char* _p = smem + 65536 + (c) * 32768 + rowB;                                    \
  _Pragma("unroll")                                                                      \
  for (int ni = 0; ni < 4; ++ni) {                                                       \
    bfr[ni][0] = *(const bf16x8*)(_p + ni * 2048 + coff0);                               \
    bfr[ni][1] = *(const bf16x8*)(_p + ni * 2048 + coff1);                               \
  }                                                                                      \
} while (0)

#define MFMA_PH(qm, nb) do {                                                             \
  __builtin_amdgcn_s_setprio(1);                                                         \
  _Pragma("unroll")                                                                      \
  for (int mi = 0; mi < 4; ++mi)                                                         \
    _Pragma("unroll")                                                                    \
    for (int nj = 0; nj < 2; ++nj)                                                       \
      _Pragma("unroll")                                                                  \
      for (int kk = 0; kk < 2; ++kk)                                                     \
        acc[(qm) * 4 + mi][(nb) * 2 + nj] = __builtin_amdgcn_mfma_f32_16x16x32_bf16(     \
            af[mi][kk], bfr[(nb) * 2 + nj][kk], acc[(qm) * 4 + mi][(nb) * 2 + nj],       \
            0, 0, 0);                                                                    \
  __builtin_amdgcn_s_setprio(0);                                                         \
} while (0)

// One K-tile = 4 phases. Stage order across phases: S4(t+1), S1(t+2), S2(t+2), S3(t+2).
// Safety: all B reads happen in ph0; A-half0 reads complete after ph2; each phase's
// closing barrier follows every wave's lgkmcnt(0), so a later phase's stage-write
// only targets LDS regions whose reads have globally retired.
#define TILE(t_, c_, doS4, doS123, VMCODE) do {                                          \
  /* ph0 */                                                                              \
  LOAD_A(0, c_); LOAD_B(c_);                                                             \
  if (doS4) STAGE_A((t_) + 1, 1, (c_) ^ 1);                                              \
  BARR(); LGKM0(); MFMA_PH(0, 0); BARR();                                                \
  /* ph1 */                                                                              \
  if (doS123) STAGE_B((t_) + 2, 0, c_);                                                  \
  BARR(); MFMA_PH(0, 1); BARR();                                                         \
  /* ph2 */                                                                              \
  LOAD_A(1, c_);                                                                         \
  if (doS123) STAGE_B((t_) + 2, 1, c_);                                                  \
  BARR(); LGKM0(); MFMA_PH(1, 1); BARR();                                                \
  /* ph3 */                                                                              \
  if (doS123) STAGE_A((t_) + 2, 0, c_);                                                  \
  BARR(); MFMA_PH(1, 0); VMCODE; BARR();                                                 \
} while (0)

__global__ __launch_bounds__(512, 2) void k_gemm(const unsigned short* __restrict__ A,
                                                 const unsigned short* __restrict__ B,
                                                 const float* __restrict__ bias,
                                                 float* __restrict__ C) {
  __shared__ char smem[131072];   // static 128 KiB (gfx950: 160 KiB/WG max)
  const int tid  = threadIdx.x;
  const int lane = tid & 63;
  const int wv   = tid >> 6;     // 0..7
  const int wm   = wv >> 2;      // 0..1
  const int wn   = wv & 3;       // 0..3
  const int r    = lane & 15;
  const int q    = lane >> 4;
  const int xr   = r & 7;
  const int coff0 = (q ^ xr) << 4;          // byte col for kk=0 (swizzled)
  const int coff1 = ((q + 4) ^ xr) << 4;    // byte col for kk=1
  const int rowA = (wm * 128 + r) * 128;    // byte row base in A tile
  const int rowB = (wn * 64 + r) * 128;     // byte row base in B tile
  const int srow = tid >> 3;                // 0..63 staging row
  const int scol = ((tid & 7) ^ ((tid >> 3) & 7)) * 8;  // pre-swizzled global elem col
  const int ldsw = wv * 1024;               // wave's byte slot in a staging round
  const int bm = blockIdx.x;                // 0..31
  const int bn = blockIdx.y;                // 0..15

  const unsigned short* Ag = A + (size_t)(bm * 256 + srow) * KDIM + scol;
  const unsigned short* Bg = B + (size_t)(bn * 256 + srow) * KDIM + scol;

  bf16x8 af[4][2], bfr[4][2];
  f32x4 acc[8][4];
  #pragma unroll
  for (int m = 0; m < 8; ++m)
    #pragma unroll
    for (int n = 0; n < 4; ++n)
      acc[m][n] = (f32x4){0.f, 0.f, 0.f, 0.f};

  // prologue: tile0 complete + 3 halves of tile1 (7 half-tiles, 14 loads/thread)
  STAGE_B(0, 0, 0); STAGE_B(0, 1, 0); STAGE_A(0, 0, 0); STAGE_A(0, 1, 0);
  STAGE_B(1, 0, 1); STAGE_B(1, 1, 1); STAGE_A(1, 0, 1);
  VMC6();   // tile0's 8 loads done; 6 in flight
  BARR();

  #pragma unroll 1
  for (int t = 0; t < 62; t += 2) {
    TILE(t,     0, 1, 1, VMC6());
    TILE(t + 1, 1, 1, 1, VMC6());
  }
  TILE(62, 0, 1, 0, VMC0());
  TILE(63, 1, 0, 0, VMC0());

  // epilogue: C = acc + bias  (C/D layout: col = r, row = q*4 + j)
  const int row0 = bm * 256 + wm * 128;
  const int col0 = bn * 256 + wn * 64;
  float bv[4];
  #pragma unroll
  for (int ni = 0; ni < 4; ++ni) bv[ni] = bias[col0 + ni * 16 + r];
  #pragma unroll
  for (int mi = 0; mi < 8; ++mi) {
    #pragma unroll
    for (int j = 0; j < 4; ++j) {
      const int row = row0 + mi * 16 + q * 4 + j;
      float* Cp = C + (size_t)row * OUT_F + col0 + r;
      #pragma unroll
      for (int ni = 0; ni < 4; ++ni)
        Cp[ni * 16] = acc[mi][ni][j] + bv[ni];
    }
  }
}

extern "C" void kernel_launch(void* const* d_in, const int* in_sizes, int n_in,
                              void* d_out, int out_size, void* d_ws, size_t ws_size,
                              hipStream_t stream) {
  const float* x    = (const float*)d_in[0];
  const int*   idx  = (const int*)d_in[1];
  const float* cb   = (const float*)d_in[2];
  const float* scl  = (const float*)d_in[3];
  const float* lA   = (const float*)d_in[4];
  const float* lB   = (const float*)d_in[5];
  const float* bias = (const float*)d_in[6];
  float* out = (float*)d_out;

  unsigned short* xb = (unsigned short*)d_ws;
  unsigned short* Wc = (unsigned short*)((char*)d_ws + (size_t)M_TOT * KDIM * 2);
  float* Lbuf = out;   // LoRA merge scratch; fully overwritten by k_gemm

  k_xcast<<<16384, 256, 0, stream>>>((const f32x4*)x, (u16x8*)xb);
  k_lora<<<dim3(16, 64), 256, 0, stream>>>(lA, lB, Lbuf);
  k_dequant<<<8192, 256, 0, stream>>>(idx, cb, scl, Lbuf, Wc);
  k_gemm<<<dim3(32, 16), 512, 0, stream>>>(xb, Wc, bias, out);
}